// Round 13
// baseline (758.932 us; speedup 1.0000x reference)
//
#include <hip/hip_runtime.h>

typedef __bf16 bf16;
typedef __bf16 bf16x8 __attribute__((ext_vector_type(8)));
typedef float f32x4 __attribute__((ext_vector_type(4)));

#define S_NB 50

// ---------------- weight pre-shuffle: f32 -> bf16 MFMA B-fragment layout ----
__global__ __launch_bounds__(256) void shuffle_w(const float* __restrict__ gatW,
                                                 bf16* __restrict__ ws) {
  int tid = blockIdx.x * 256 + threadIdx.x;
  if (tid >= 6 * 512) return;
  int mat = tid >> 9;
  int rem = tid & 511;
  int ks = rem >> 8;
  int nt = (rem >> 6) & 3;
  int lane = rem & 63;
  int t = mat >> 1, p = (mat & 1) + 1;
  const float* src = gatW + (size_t)(t * 4 + p) * 4096;
  int n = nt * 16 + (lane & 15);
  int kb = ks * 32 + (lane >> 4) * 8;
  bf16x8 v;
#pragma unroll
  for (int e = 0; e < 8; ++e) v[e] = (bf16)src[(kb + e) * 64 + n];
  *reinterpret_cast<bf16x8*>(ws + mat * 4096 + ((ks * 4 + nt) * 64 + lane) * 8) = v;
}

// ---------------- 4-batch fused layers (r11 math; eb/y aliased away) --------
struct Smem {
  float node[4][64];    // 1 KB
  float qp[4][64];      // 1 KB
  float sc[4][64];      // 1 KB (scores, then probs in place)
  float yp[4][4][64];   // 4 KB ([j][wave][col]; row 0 doubles as y)
  float kvp[4][6][64];  // 6 KB (row 0 doubles as sem-y)
  float aggb[2][4][64]; // 2 KB
};                      // 15360 B per sub-group

__device__ __forceinline__ void gat_layer4(
    int b0, const int* idx, const float* table, const float* Wt,
    const float* bt, const bf16* frags, float (*aggdst)[64], Smem* sm,
    int wave, int lane) {
  int c15 = lane & 15;
  int g = lane >> 4;
  int arow = wave * 16 + c15;
  int rbase = wave * 16 + g * 4;

  // A fragments: 4 batches x 2 k-halves (rows 50..63 -> id 0 = zero row)
  bf16x8 af0[4], af1[4];
#pragma unroll
  for (int j = 0; j < 4; ++j) {
    int id = (arow < S_NB) ? idx[(b0 + j) * S_NB + arow] : 0;
    const float* rowp = table + (size_t)id * 64;
    float4 f0 = *reinterpret_cast<const float4*>(rowp + g * 8);
    float4 f1 = *reinterpret_cast<const float4*>(rowp + g * 8 + 4);
    float4 f2 = *reinterpret_cast<const float4*>(rowp + 32 + g * 8);
    float4 f3 = *reinterpret_cast<const float4*>(rowp + 32 + g * 8 + 4);
    af0[j][0] = (bf16)f0.x; af0[j][1] = (bf16)f0.y; af0[j][2] = (bf16)f0.z; af0[j][3] = (bf16)f0.w;
    af0[j][4] = (bf16)f1.x; af0[j][5] = (bf16)f1.y; af0[j][6] = (bf16)f1.z; af0[j][7] = (bf16)f1.w;
    af1[j][0] = (bf16)f2.x; af1[j][1] = (bf16)f2.y; af1[j][2] = (bf16)f2.z; af1[j][3] = (bf16)f2.w;
    af1[j][4] = (bf16)f3.x; af1[j][5] = (bf16)f3.y; af1[j][6] = (bf16)f3.z; af1[j][7] = (bf16)f3.w;
  }

  // Phase B: qp col-parallel (j = wave, col = lane)
  {
    const float* src = sm->node[wave];
    float a0 = 0.f, a1 = 0.f, a2 = 0.f, a3 = 0.f;
#pragma unroll 4
    for (int kk = 0; kk < 16; ++kk) {
      a0 += src[kk] * Wt[kk * 64 + lane];
      a1 += src[16 + kk] * Wt[(16 + kk) * 64 + lane];
      a2 += src[32 + kk] * Wt[(32 + kk) * 64 + lane];
      a3 += src[48 + kk] * Wt[(48 + kk) * 64 + lane];
    }
    sm->qp[wave][lane] = fmaxf((((a0 + a1) + a2) + a3) + bt[lane], 0.f);
  }
  __syncthreads();  // (1) qp visible

  // Phase C: K-proj MFMA (B-frags shared across 4 batches) + folded scores
  float s[4][4];
#pragma unroll
  for (int j = 0; j < 4; ++j)
#pragma unroll
    for (int e = 0; e < 4; ++e) s[j][e] = 0.f;
#pragma unroll
  for (int nt = 0; nt < 4; ++nt) {
    bf16x8 bk0 = *reinterpret_cast<const bf16x8*>(frags + ((0 * 4 + nt) * 64 + lane) * 8);
    bf16x8 bk1 = *reinterpret_cast<const bf16x8*>(frags + ((1 * 4 + nt) * 64 + lane) * 8);
    float kb = bt[64 + nt * 16 + c15];
#pragma unroll
    for (int j = 0; j < 4; ++j) {
      f32x4 acc = {0.f, 0.f, 0.f, 0.f};
      acc = __builtin_amdgcn_mfma_f32_16x16x32_bf16(af0[j], bk0, acc, 0, 0, 0);
      acc = __builtin_amdgcn_mfma_f32_16x16x32_bf16(af1[j], bk1, acc, 0, 0, 0);
      float qv = sm->qp[j][nt * 16 + c15];
#pragma unroll
      for (int e = 0; e < 4; ++e) s[j][e] += fmaxf(acc[e] + kb, 0.f) * qv;
    }
  }
#pragma unroll
  for (int m = 1; m < 16; m <<= 1)
#pragma unroll
    for (int j = 0; j < 4; ++j)
#pragma unroll
      for (int e = 0; e < 4; ++e) s[j][e] += __shfl_xor(s[j][e], m, 64);
  if (c15 == 0) {
#pragma unroll
    for (int j = 0; j < 4; ++j)
#pragma unroll
      for (int e = 0; e < 4; ++e) sm->sc[j][rbase + e] = s[j][e];
  }
  __syncthreads();  // (2) scores visible

  // Phase D: softmax, one chain per wave (probs written into sc in place;
  // within-wave read-then-write is lockstep-ordered, cross-wave rows disjoint)
  {
    int j = wave;
    float mx = -1e30f;
    for (int i = 0; i < S_NB; ++i) mx = fmaxf(mx, sm->sc[j][i]);
    float ev = (lane < S_NB) ? __expf((sm->sc[j][lane] - mx) * 0.125f) : 0.f;
    sm->sc[j][lane] = ev;
  }
  __syncthreads();  // (3) probs visible
  float rden;
  {
    int j = wave;
    float den = 0.f;
    for (int i = 0; i < S_NB; ++i) den += sm->sc[j][i];
    rden = 1.f / den;
  }

  // Phase E: V-proj MFMA + folded PV
  float ew[4][4];
#pragma unroll
  for (int j = 0; j < 4; ++j)
#pragma unroll
    for (int e = 0; e < 4; ++e) ew[j][e] = sm->sc[j][rbase + e];
#pragma unroll
  for (int nt = 0; nt < 4; ++nt) {
    bf16x8 bv0 = *reinterpret_cast<const bf16x8*>(frags + 4096 + ((0 * 4 + nt) * 64 + lane) * 8);
    bf16x8 bv1 = *reinterpret_cast<const bf16x8*>(frags + 4096 + ((1 * 4 + nt) * 64 + lane) * 8);
    float vb = bt[128 + nt * 16 + c15];
#pragma unroll
    for (int j = 0; j < 4; ++j) {
      f32x4 acc = {0.f, 0.f, 0.f, 0.f};
      acc = __builtin_amdgcn_mfma_f32_16x16x32_bf16(af0[j], bv0, acc, 0, 0, 0);
      acc = __builtin_amdgcn_mfma_f32_16x16x32_bf16(af1[j], bv1, acc, 0, 0, 0);
      float p = ew[j][0] * fmaxf(acc[0] + vb, 0.f) +
                ew[j][1] * fmaxf(acc[1] + vb, 0.f) +
                ew[j][2] * fmaxf(acc[2] + vb, 0.f) +
                ew[j][3] * fmaxf(acc[3] + vb, 0.f);
      p += __shfl_xor(p, 16, 64);
      p += __shfl_xor(p, 32, 64);
      if (lane < 16) sm->yp[j][wave][nt * 16 + lane] = p;
    }
  }
  __syncthreads();  // (4) yp visible

  // Phase F: y reduce into yp[wave][0] (in place; per-thread same-address)
  sm->yp[wave][0][lane] = (((sm->yp[wave][0][lane] + sm->yp[wave][1][lane]) +
                            sm->yp[wave][2][lane]) + sm->yp[wave][3][lane]) * rden;
  __syncthreads();  // (5) y visible

  // Phase G: agg = relu(y @ W3 + b3), col-parallel
  {
    const float* W3 = Wt + 3 * 4096;
    const float* src = sm->yp[wave][0];
    float a0 = 0.f, a1 = 0.f, a2 = 0.f, a3 = 0.f;
#pragma unroll 4
    for (int kk = 0; kk < 16; ++kk) {
      a0 += src[kk] * W3[kk * 64 + lane];
      a1 += src[16 + kk] * W3[(16 + kk) * 64 + lane];
      a2 += src[32 + kk] * W3[(32 + kk) * 64 + lane];
      a3 += src[48 + kk] * W3[(48 + kk) * 64 + lane];
    }
    aggdst[wave][lane] = fmaxf((((a0 + a1) + a2) + a3) + bt[192 + lane], 0.f);
  }
  __syncthreads();  // (6) agg visible
}

__device__ __forceinline__ void sem_layer4(
    int ns, int b0, int toff, const float* Wt, const float* bt, float* out,
    Smem* sm, int wave, int lane, int stid) {
  // qp col-parallel (j = wave)
  {
    const float* src = sm->node[wave];
    float a0 = 0.f, a1 = 0.f, a2 = 0.f, a3 = 0.f;
#pragma unroll 4
    for (int kk = 0; kk < 16; ++kk) {
      a0 += src[kk] * Wt[kk * 64 + lane];
      a1 += src[16 + kk] * Wt[(16 + kk) * 64 + lane];
      a2 += src[32 + kk] * Wt[(32 + kk) * 64 + lane];
      a3 += src[48 + kk] * Wt[(48 + kk) * 64 + lane];
    }
    sm->qp[wave][lane] = fmaxf((((a0 + a1) + a2) + a3) + bt[lane], 0.f);
  }
  __syncthreads();  // (1)

  // kp/vp cells: (proj, r, n), 4 j accumulators share each weight load
  for (int cc = stid; cc < 2 * ns * 64; cc += 256) {
    int proj = cc / (ns * 64);
    int r = (cc >> 6) % ns;
    int n = cc & 63;
    const float* w = Wt + (size_t)(proj + 1) * 4096;
    const float* sN = (r == 0) ? &sm->node[0][0] : &sm->aggb[r - 1][0][0];
    float acc0 = bt[(proj + 1) * 64 + n];
    float acc1 = acc0, acc2 = acc0, acc3 = acc0;
#pragma unroll 8
    for (int k = 0; k < 64; ++k) {
      float wv = w[k * 64 + n];
      acc0 += sN[k] * wv;
      acc1 += sN[64 + k] * wv;
      acc2 += sN[128 + k] * wv;
      acc3 += sN[192 + k] * wv;
    }
    sm->kvp[0][proj * 3 + r][n] = fmaxf(acc0, 0.f);
    sm->kvp[1][proj * 3 + r][n] = fmaxf(acc1, 0.f);
    sm->kvp[2][proj * 3 + r][n] = fmaxf(acc2, 0.f);
    sm->kvp[3][proj * 3 + r][n] = fmaxf(acc3, 0.f);
  }
  __syncthreads();  // (2)

  // scores: thread (j, r)
  if (stid < 4 * ns) {
    int j = stid / ns, r = stid - (stid / ns) * ns;
    float acc = 0.f;
#pragma unroll 8
    for (int k = 0; k < 64; ++k) acc += sm->qp[j][k] * sm->kvp[j][r][k];
    sm->sc[j][r] = acc * 0.125f;
  }
  __syncthreads();  // (3)

  // softmax over ns + y into kvp[j][0] (kp rows dead after scores)
  {
    int j = wave;
    float mx = sm->sc[j][0];
    for (int i = 1; i < ns; ++i) mx = fmaxf(mx, sm->sc[j][i]);
    float e0 = __expf(sm->sc[j][0] - mx);
    float e1 = __expf(sm->sc[j][1] - mx);
    float e2 = (ns > 2) ? __expf(sm->sc[j][2] - mx) : 0.f;
    float rd = 1.f / (e0 + e1 + e2);
    float yv = e0 * sm->kvp[j][3][lane] + e1 * sm->kvp[j][4][lane];
    if (ns > 2) yv += e2 * sm->kvp[j][5][lane];
    sm->kvp[j][0][lane] = yv * rd;
  }
  __syncthreads();  // (4)

  // out = relu(y @ W3 + b3) -> global f32, col-parallel
  {
    const float* W3 = Wt + 3 * 4096;
    const float* src = sm->kvp[wave][0];
    float a0 = 0.f, a1 = 0.f, a2 = 0.f, a3 = 0.f;
#pragma unroll 4
    for (int kk = 0; kk < 16; ++kk) {
      a0 += src[kk] * W3[kk * 64 + lane];
      a1 += src[16 + kk] * W3[(16 + kk) * 64 + lane];
      a2 += src[32 + kk] * W3[(32 + kk) * 64 + lane];
      a3 += src[48 + kk] * W3[(48 + kk) * 64 + lane];
    }
    out[(size_t)(b0 + wave) * 192 + toff + lane] =
        fmaxf((((a0 + a1) + a2) + a3) + bt[192 + lane], 0.f);
  }
}

// ---- 1024-thread blocks = 4 independent sub-groups (same tower) ------------
// launch_bounds min-waves dropped: r12's (1024,4) squeezed VGPR to 64 and
// spilled (WRITE_SIZE 589 MB). (1024,1) lets the allocator use up to 128.
__global__ __launch_bounds__(1024, 1) void fused_towers(
    const int* __restrict__ uids, const int* __restrict__ qids,
    const int* __restrict__ mids, const int* __restrict__ u_movies,
    const int* __restrict__ m_querys, const int* __restrict__ m_users,
    const int* __restrict__ q_movies, const float* __restrict__ user_t,
    const float* __restrict__ item_t, const float* __restrict__ query_t,
    const float* __restrict__ gatW, const float* __restrict__ gatB,
    const float* __restrict__ semW, const float* __restrict__ semB,
    const bf16* __restrict__ wfrag, float* __restrict__ out) {
  __shared__ Smem smArr[4];  // 61440 B

  int nbB = gridDim.x / 3;
  int tower = blockIdx.x / nbB;  // 0:U 1:M 2:Q (block-uniform)
  int blk = blockIdx.x - tower * nbB;
  int tid1k = threadIdx.x;
  int sub = tid1k >> 8;
  int stid = tid1k & 255;
  int lane = tid1k & 63;
  int wave = (tid1k >> 6) & 3;
  Smem* sm = &smArr[sub];
  int b0 = blk * 16 + sub * 4;

  // node rows: thread (sub, j = wave, n = lane)
  {
    int bj = b0 + wave;
    int id = (tower == 0) ? uids[bj] : (tower == 1 ? mids[bj] : qids[bj]);
    const float* tab = (tower == 0) ? user_t : (tower == 1 ? item_t : query_t);
    sm->node[wave][lane] = tab[(size_t)id * 64 + lane];
  }
  __syncthreads();

  if (tower == 0) {
    gat_layer4(b0, u_movies, item_t, gatW, gatB, wfrag, sm->aggb[0], sm,
               wave, lane);
    sem_layer4(2, b0, 0, semW, semB, out, sm, wave, lane, stid);
  } else if (tower == 1) {
    gat_layer4(b0, m_querys, query_t, gatW + 4 * 4096, gatB + 256,
               wfrag + 8192, sm->aggb[0], sm, wave, lane);
    gat_layer4(b0, m_users, user_t, gatW + 4 * 4096, gatB + 256,
               wfrag + 8192, sm->aggb[1], sm, wave, lane);
    sem_layer4(3, b0, 64, semW + 4 * 4096, semB + 256, out, sm, wave, lane, stid);
  } else {
    gat_layer4(b0, q_movies, item_t, gatW + 8 * 4096, gatB + 512,
               wfrag + 16384, sm->aggb[0], sm, wave, lane);
    sem_layer4(2, b0, 128, semW + 8 * 4096, semB + 512, out, sm, wave, lane, stid);
  }
}

extern "C" void kernel_launch(void* const* d_in, const int* in_sizes, int n_in,
                              void* d_out, int out_size, void* d_ws, size_t ws_size,
                              hipStream_t stream) {
  const int* uids = (const int*)d_in[0];
  const int* qids = (const int*)d_in[1];
  const int* mids = (const int*)d_in[2];
  const int* u_movies = (const int*)d_in[3];
  const int* m_querys = (const int*)d_in[4];
  const int* m_users = (const int*)d_in[5];
  const int* q_movies = (const int*)d_in[6];
  const float* user_t = (const float*)d_in[7];
  const float* item_t = (const float*)d_in[8];
  const float* query_t = (const float*)d_in[9];
  const float* gatW = (const float*)d_in[10];
  const float* gatB = (const float*)d_in[11];
  const float* semW = (const float*)d_in[12];
  const float* semB = (const float*)d_in[13];
  float* out = (float*)d_out;
  bf16* wfrag = (bf16*)d_ws; // 6*4096*2 = 48 KiB

  int B = in_sizes[0];
  int nbB = B / 16;  // B = 16384, divisible by 16
  shuffle_w<<<12, 256, 0, stream>>>(gatW, wfrag);
  fused_towers<<<3 * nbB, 1024, 0, stream>>>(uids, qids, mids, u_movies,
                                             m_querys, m_users, q_movies,
                                             user_t, item_t, query_t, gatW,
                                             gatB, semW, semB, wfrag, out);
}

// Round 14
// 691.413 us; speedup vs baseline: 1.0977x; 1.0977x over previous
//
#include <hip/hip_runtime.h>

typedef __bf16 bf16;
typedef __bf16 bf16x8 __attribute__((ext_vector_type(8)));
typedef float f32x4 __attribute__((ext_vector_type(4)));

#define S_NB 50

// ---------------- weight pre-shuffle: f32 -> bf16 MFMA B-fragment layout ----
__global__ __launch_bounds__(256) void shuffle_w(const float* __restrict__ gatW,
                                                 bf16* __restrict__ ws) {
  int tid = blockIdx.x * 256 + threadIdx.x;
  if (tid >= 6 * 512) return;
  int mat = tid >> 9;
  int rem = tid & 511;
  int ks = rem >> 8;
  int nt = (rem >> 6) & 3;
  int lane = rem & 63;
  int t = mat >> 1, p = (mat & 1) + 1;
  const float* src = gatW + (size_t)(t * 4 + p) * 4096;
  int n = nt * 16 + (lane & 15);
  int kb = ks * 32 + (lane >> 4) * 8;
  bf16x8 v;
#pragma unroll
  for (int e = 0; e < 8; ++e) v[e] = (bf16)src[(kb + e) * 64 + n];
  *reinterpret_cast<bf16x8*>(ws + mat * 4096 + ((ks * 4 + nt) * 64 + lane) * 8) = v;
}

// ---------------- 4-batch fused layers (r11 math; eb/y aliased away) --------
struct Smem {
  float node[4][64];    // 1 KB
  float qp[4][64];      // 1 KB
  float sc[4][64];      // 1 KB (scores, then probs in place)
  float yp[4][4][64];   // 4 KB ([j][wave][col]; row 0 doubles as y)
  float kvp[4][6][64];  // 6 KB (row 0 doubles as sem-y)
  float aggb[2][4][64]; // 2 KB
};                      // 15360 B per sub-group

__device__ __forceinline__ void gat_layer4(
    int b0, const int* idx, const float* table, const float* Wt,
    const float* bt, const bf16* frags, float (*aggdst)[64], Smem* sm,
    int wave, int lane) {
  int c15 = lane & 15;
  int g = lane >> 4;
  int arow = wave * 16 + c15;
  int rbase = wave * 16 + g * 4;

  // A fragments: 4 batches x 2 k-halves (rows 50..63 -> id 0 = zero row)
  bf16x8 af0[4], af1[4];
#pragma unroll
  for (int j = 0; j < 4; ++j) {
    int id = (arow < S_NB) ? idx[(b0 + j) * S_NB + arow] : 0;
    const float* rowp = table + (size_t)id * 64;
    float4 f0 = *reinterpret_cast<const float4*>(rowp + g * 8);
    float4 f1 = *reinterpret_cast<const float4*>(rowp + g * 8 + 4);
    float4 f2 = *reinterpret_cast<const float4*>(rowp + 32 + g * 8);
    float4 f3 = *reinterpret_cast<const float4*>(rowp + 32 + g * 8 + 4);
    af0[j][0] = (bf16)f0.x; af0[j][1] = (bf16)f0.y; af0[j][2] = (bf16)f0.z; af0[j][3] = (bf16)f0.w;
    af0[j][4] = (bf16)f1.x; af0[j][5] = (bf16)f1.y; af0[j][6] = (bf16)f1.z; af0[j][7] = (bf16)f1.w;
    af1[j][0] = (bf16)f2.x; af1[j][1] = (bf16)f2.y; af1[j][2] = (bf16)f2.z; af1[j][3] = (bf16)f2.w;
    af1[j][4] = (bf16)f3.x; af1[j][5] = (bf16)f3.y; af1[j][6] = (bf16)f3.z; af1[j][7] = (bf16)f3.w;
  }

  // Phase B: qp col-parallel (j = wave, col = lane)
  {
    const float* src = sm->node[wave];
    float a0 = 0.f, a1 = 0.f, a2 = 0.f, a3 = 0.f;
#pragma unroll 4
    for (int kk = 0; kk < 16; ++kk) {
      a0 += src[kk] * Wt[kk * 64 + lane];
      a1 += src[16 + kk] * Wt[(16 + kk) * 64 + lane];
      a2 += src[32 + kk] * Wt[(32 + kk) * 64 + lane];
      a3 += src[48 + kk] * Wt[(48 + kk) * 64 + lane];
    }
    sm->qp[wave][lane] = fmaxf((((a0 + a1) + a2) + a3) + bt[lane], 0.f);
  }
  __syncthreads();  // (1) qp visible

  // Phase C: K-proj MFMA (B-frags shared across 4 batches) + folded scores
  float s[4][4];
#pragma unroll
  for (int j = 0; j < 4; ++j)
#pragma unroll
    for (int e = 0; e < 4; ++e) s[j][e] = 0.f;
#pragma unroll
  for (int nt = 0; nt < 4; ++nt) {
    bf16x8 bk0 = *reinterpret_cast<const bf16x8*>(frags + ((0 * 4 + nt) * 64 + lane) * 8);
    bf16x8 bk1 = *reinterpret_cast<const bf16x8*>(frags + ((1 * 4 + nt) * 64 + lane) * 8);
    float kb = bt[64 + nt * 16 + c15];
#pragma unroll
    for (int j = 0; j < 4; ++j) {
      f32x4 acc = {0.f, 0.f, 0.f, 0.f};
      acc = __builtin_amdgcn_mfma_f32_16x16x32_bf16(af0[j], bk0, acc, 0, 0, 0);
      acc = __builtin_amdgcn_mfma_f32_16x16x32_bf16(af1[j], bk1, acc, 0, 0, 0);
      float qv = sm->qp[j][nt * 16 + c15];
#pragma unroll
      for (int e = 0; e < 4; ++e) s[j][e] += fmaxf(acc[e] + kb, 0.f) * qv;
    }
  }
#pragma unroll
  for (int m = 1; m < 16; m <<= 1)
#pragma unroll
    for (int j = 0; j < 4; ++j)
#pragma unroll
      for (int e = 0; e < 4; ++e) s[j][e] += __shfl_xor(s[j][e], m, 64);
  if (c15 == 0) {
#pragma unroll
    for (int j = 0; j < 4; ++j)
#pragma unroll
      for (int e = 0; e < 4; ++e) sm->sc[j][rbase + e] = s[j][e];
  }
  __syncthreads();  // (2) scores visible

  // Phase D: softmax, one chain per wave (probs written into sc in place)
  {
    int j = wave;
    float mx = -1e30f;
    for (int i = 0; i < S_NB; ++i) mx = fmaxf(mx, sm->sc[j][i]);
    float ev = (lane < S_NB) ? __expf((sm->sc[j][lane] - mx) * 0.125f) : 0.f;
    sm->sc[j][lane] = ev;
  }
  __syncthreads();  // (3) probs visible
  float rden;
  {
    int j = wave;
    float den = 0.f;
    for (int i = 0; i < S_NB; ++i) den += sm->sc[j][i];
    rden = 1.f / den;
  }

  // Phase E: V-proj MFMA + folded PV
  float ew[4][4];
#pragma unroll
  for (int j = 0; j < 4; ++j)
#pragma unroll
    for (int e = 0; e < 4; ++e) ew[j][e] = sm->sc[j][rbase + e];
#pragma unroll
  for (int nt = 0; nt < 4; ++nt) {
    bf16x8 bv0 = *reinterpret_cast<const bf16x8*>(frags + 4096 + ((0 * 4 + nt) * 64 + lane) * 8);
    bf16x8 bv1 = *reinterpret_cast<const bf16x8*>(frags + 4096 + ((1 * 4 + nt) * 64 + lane) * 8);
    float vb = bt[128 + nt * 16 + c15];
#pragma unroll
    for (int j = 0; j < 4; ++j) {
      f32x4 acc = {0.f, 0.f, 0.f, 0.f};
      acc = __builtin_amdgcn_mfma_f32_16x16x32_bf16(af0[j], bv0, acc, 0, 0, 0);
      acc = __builtin_amdgcn_mfma_f32_16x16x32_bf16(af1[j], bv1, acc, 0, 0, 0);
      float p = ew[j][0] * fmaxf(acc[0] + vb, 0.f) +
                ew[j][1] * fmaxf(acc[1] + vb, 0.f) +
                ew[j][2] * fmaxf(acc[2] + vb, 0.f) +
                ew[j][3] * fmaxf(acc[3] + vb, 0.f);
      p += __shfl_xor(p, 16, 64);
      p += __shfl_xor(p, 32, 64);
      if (lane < 16) sm->yp[j][wave][nt * 16 + lane] = p;
    }
  }
  __syncthreads();  // (4) yp visible

  // Phase F: y reduce into yp[wave][0] (in place; per-thread same-address)
  sm->yp[wave][0][lane] = (((sm->yp[wave][0][lane] + sm->yp[wave][1][lane]) +
                            sm->yp[wave][2][lane]) + sm->yp[wave][3][lane]) * rden;
  __syncthreads();  // (5) y visible

  // Phase G: agg = relu(y @ W3 + b3), col-parallel
  {
    const float* W3 = Wt + 3 * 4096;
    const float* src = sm->yp[wave][0];
    float a0 = 0.f, a1 = 0.f, a2 = 0.f, a3 = 0.f;
#pragma unroll 4
    for (int kk = 0; kk < 16; ++kk) {
      a0 += src[kk] * W3[kk * 64 + lane];
      a1 += src[16 + kk] * W3[(16 + kk) * 64 + lane];
      a2 += src[32 + kk] * W3[(32 + kk) * 64 + lane];
      a3 += src[48 + kk] * W3[(48 + kk) * 64 + lane];
    }
    aggdst[wave][lane] = fmaxf((((a0 + a1) + a2) + a3) + bt[192 + lane], 0.f);
  }
  __syncthreads();  // (6) agg visible
}

__device__ __forceinline__ void sem_layer4(
    int ns, int b0, int toff, const float* Wt, const float* bt, float* out,
    Smem* sm, int wave, int lane, int stid) {
  // qp col-parallel (j = wave)
  {
    const float* src = sm->node[wave];
    float a0 = 0.f, a1 = 0.f, a2 = 0.f, a3 = 0.f;
#pragma unroll 4
    for (int kk = 0; kk < 16; ++kk) {
      a0 += src[kk] * Wt[kk * 64 + lane];
      a1 += src[16 + kk] * Wt[(16 + kk) * 64 + lane];
      a2 += src[32 + kk] * Wt[(32 + kk) * 64 + lane];
      a3 += src[48 + kk] * Wt[(48 + kk) * 64 + lane];
    }
    sm->qp[wave][lane] = fmaxf((((a0 + a1) + a2) + a3) + bt[lane], 0.f);
  }
  __syncthreads();  // (1)

  // kp/vp cells: (proj, r, n), 4 j accumulators share each weight load
  for (int cc = stid; cc < 2 * ns * 64; cc += 256) {
    int proj = cc / (ns * 64);
    int r = (cc >> 6) % ns;
    int n = cc & 63;
    const float* w = Wt + (size_t)(proj + 1) * 4096;
    const float* sN = (r == 0) ? &sm->node[0][0] : &sm->aggb[r - 1][0][0];
    float acc0 = bt[(proj + 1) * 64 + n];
    float acc1 = acc0, acc2 = acc0, acc3 = acc0;
#pragma unroll 8
    for (int k = 0; k < 64; ++k) {
      float wv = w[k * 64 + n];
      acc0 += sN[k] * wv;
      acc1 += sN[64 + k] * wv;
      acc2 += sN[128 + k] * wv;
      acc3 += sN[192 + k] * wv;
    }
    sm->kvp[0][proj * 3 + r][n] = fmaxf(acc0, 0.f);
    sm->kvp[1][proj * 3 + r][n] = fmaxf(acc1, 0.f);
    sm->kvp[2][proj * 3 + r][n] = fmaxf(acc2, 0.f);
    sm->kvp[3][proj * 3 + r][n] = fmaxf(acc3, 0.f);
  }
  __syncthreads();  // (2)

  // scores: thread (j, r)
  if (stid < 4 * ns) {
    int j = stid / ns, r = stid - (stid / ns) * ns;
    float acc = 0.f;
#pragma unroll 8
    for (int k = 0; k < 64; ++k) acc += sm->qp[j][k] * sm->kvp[j][r][k];
    sm->sc[j][r] = acc * 0.125f;
  }
  __syncthreads();  // (3)

  // softmax over ns + y into kvp[j][0] (kp rows dead after scores)
  {
    int j = wave;
    float mx = sm->sc[j][0];
    for (int i = 1; i < ns; ++i) mx = fmaxf(mx, sm->sc[j][i]);
    float e0 = __expf(sm->sc[j][0] - mx);
    float e1 = __expf(sm->sc[j][1] - mx);
    float e2 = (ns > 2) ? __expf(sm->sc[j][2] - mx) : 0.f;
    float rd = 1.f / (e0 + e1 + e2);
    float yv = e0 * sm->kvp[j][3][lane] + e1 * sm->kvp[j][4][lane];
    if (ns > 2) yv += e2 * sm->kvp[j][5][lane];
    sm->kvp[j][0][lane] = yv * rd;
  }
  __syncthreads();  // (4)

  // out = relu(y @ W3 + b3) -> global f32, col-parallel
  {
    const float* W3 = Wt + 3 * 4096;
    const float* src = sm->kvp[wave][0];
    float a0 = 0.f, a1 = 0.f, a2 = 0.f, a3 = 0.f;
#pragma unroll 4
    for (int kk = 0; kk < 16; ++kk) {
      a0 += src[kk] * W3[kk * 64 + lane];
      a1 += src[16 + kk] * W3[(16 + kk) * 64 + lane];
      a2 += src[32 + kk] * W3[(32 + kk) * 64 + lane];
      a3 += src[48 + kk] * W3[(48 + kk) * 64 + lane];
    }
    out[(size_t)(b0 + wave) * 192 + toff + lane] =
        fmaxf((((a0 + a1) + a2) + a3) + bt[192 + lane], 0.f);
  }
}

// ---- 512-thread blocks = 2 independent sub-groups (same tower) -------------
// r12/13 lesson: 1024-thread blocks force VGPR=64 -> spills (WRITE 589 MB).
// 512-thread needs only 2 waves/SIMD co-resident -> compiler keeps ~112 VGPR.
__global__ __launch_bounds__(512) void fused_towers(
    const int* __restrict__ uids, const int* __restrict__ qids,
    const int* __restrict__ mids, const int* __restrict__ u_movies,
    const int* __restrict__ m_querys, const int* __restrict__ m_users,
    const int* __restrict__ q_movies, const float* __restrict__ user_t,
    const float* __restrict__ item_t, const float* __restrict__ query_t,
    const float* __restrict__ gatW, const float* __restrict__ gatB,
    const float* __restrict__ semW, const float* __restrict__ semB,
    const bf16* __restrict__ wfrag, float* __restrict__ out) {
  __shared__ Smem smArr[2];  // 30720 B

  int nbB = gridDim.x / 3;
  int tower = blockIdx.x / nbB;  // 0:U 1:M 2:Q (block-uniform)
  int blk = blockIdx.x - tower * nbB;
  int tid5 = threadIdx.x;
  int sub = tid5 >> 8;
  int stid = tid5 & 255;
  int lane = tid5 & 63;
  int wave = (tid5 >> 6) & 3;
  Smem* sm = &smArr[sub];
  int b0 = blk * 8 + sub * 4;

  // node rows: thread (sub, j = wave, n = lane)
  {
    int bj = b0 + wave;
    int id = (tower == 0) ? uids[bj] : (tower == 1 ? mids[bj] : qids[bj]);
    const float* tab = (tower == 0) ? user_t : (tower == 1 ? item_t : query_t);
    sm->node[wave][lane] = tab[(size_t)id * 64 + lane];
  }
  __syncthreads();

  if (tower == 0) {
    gat_layer4(b0, u_movies, item_t, gatW, gatB, wfrag, sm->aggb[0], sm,
               wave, lane);
    sem_layer4(2, b0, 0, semW, semB, out, sm, wave, lane, stid);
  } else if (tower == 1) {
    gat_layer4(b0, m_querys, query_t, gatW + 4 * 4096, gatB + 256,
               wfrag + 8192, sm->aggb[0], sm, wave, lane);
    gat_layer4(b0, m_users, user_t, gatW + 4 * 4096, gatB + 256,
               wfrag + 8192, sm->aggb[1], sm, wave, lane);
    sem_layer4(3, b0, 64, semW + 4 * 4096, semB + 256, out, sm, wave, lane, stid);
  } else {
    gat_layer4(b0, q_movies, item_t, gatW + 8 * 4096, gatB + 512,
               wfrag + 16384, sm->aggb[0], sm, wave, lane);
    sem_layer4(2, b0, 128, semW + 8 * 4096, semB + 512, out, sm, wave, lane, stid);
  }
}

extern "C" void kernel_launch(void* const* d_in, const int* in_sizes, int n_in,
                              void* d_out, int out_size, void* d_ws, size_t ws_size,
                              hipStream_t stream) {
  const int* uids = (const int*)d_in[0];
  const int* qids = (const int*)d_in[1];
  const int* mids = (const int*)d_in[2];
  const int* u_movies = (const int*)d_in[3];
  const int* m_querys = (const int*)d_in[4];
  const int* m_users = (const int*)d_in[5];
  const int* q_movies = (const int*)d_in[6];
  const float* user_t = (const float*)d_in[7];
  const float* item_t = (const float*)d_in[8];
  const float* query_t = (const float*)d_in[9];
  const float* gatW = (const float*)d_in[10];
  const float* gatB = (const float*)d_in[11];
  const float* semW = (const float*)d_in[12];
  const float* semB = (const float*)d_in[13];
  float* out = (float*)d_out;
  bf16* wfrag = (bf16*)d_ws; // 6*4096*2 = 48 KiB

  int B = in_sizes[0];
  int nbB = B / 8;  // B = 16384, divisible by 8
  shuffle_w<<<12, 256, 0, stream>>>(gatW, wfrag);
  fused_towers<<<3 * nbB, 512, 0, stream>>>(uids, qids, mids, u_movies,
                                            m_querys, m_users, q_movies,
                                            user_t, item_t, query_t, gatW,
                                            gatB, semW, semB, wfrag, out);
}